// Round 2
// baseline (1007.306 us; speedup 1.0000x reference)
//
#include <hip/hip_runtime.h>

typedef unsigned short u16;
typedef __attribute__((ext_vector_type(8))) short bf16x8;
typedef __attribute__((ext_vector_type(4))) short bf16x4;
typedef __attribute__((ext_vector_type(4))) float f32x4;

#define AS1 __attribute__((address_space(1)))
#define AS3 __attribute__((address_space(3)))

__device__ __forceinline__ float bf2f(u16 u) {
  union { unsigned int i; float f; } v; v.i = ((unsigned int)u) << 16; return v.f;
}
__device__ __forceinline__ u16 f2bf(float f) {
  union { float f; unsigned int i; } v; v.f = f;
  return (u16)((v.i + 0x7fffu + ((v.i >> 16) & 1u)) >> 16);
}

// ---------------- hidden_states fp32 -> bf16 ----------------
__global__ __launch_bounds__(256) void cvt_hs(const float* __restrict__ in, u16* __restrict__ out) {
  size_t i = ((size_t)blockIdx.x * 256 + threadIdx.x) * 8;
  float4 a = *(const float4*)(in + i);
  float4 b = *(const float4*)(in + i + 4);
  bf16x8 o;
  o[0] = (short)f2bf(a.x); o[1] = (short)f2bf(a.y); o[2] = (short)f2bf(a.z); o[3] = (short)f2bf(a.w);
  o[4] = (short)f2bf(b.x); o[5] = (short)f2bf(b.y); o[6] = (short)f2bf(b.z); o[7] = (short)f2bf(b.w);
  *(bf16x8*)(out + i) = o;
}

// ---------------- weight transpose: W fp32 (2560 x 2560, K x N) -> WT bf16 (N x K) ----------------
__global__ __launch_bounds__(256) void transp_k(
    const float* __restrict__ Wq, const float* __restrict__ Wk,
    const float* __restrict__ Wv, const float* __restrict__ Wo,
    u16* __restrict__ WqT, u16* __restrict__ WkT,
    u16* __restrict__ WvT, u16* __restrict__ WoT)
{
  __shared__ u16 tile[64][65];
  const float* W; u16* WT;
  switch (blockIdx.z) {
    case 0: W = Wq; WT = WqT; break;
    case 1: W = Wk; WT = WkT; break;
    case 2: W = Wv; WT = WvT; break;
    default: W = Wo; WT = WoT; break;
  }
  const int n0 = blockIdx.x * 64, k0 = blockIdx.y * 64;
  const int t = threadIdx.x;
  const int r = t >> 2, c4 = (t & 3) * 16;
  const float* src = W + (size_t)(k0 + r) * 2560 + n0 + c4;
#pragma unroll
  for (int i = 0; i < 16; i += 4) {
    float4 v = *(const float4*)(src + i);
    tile[r][c4 + i + 0] = f2bf(v.x);
    tile[r][c4 + i + 1] = f2bf(v.y);
    tile[r][c4 + i + 2] = f2bf(v.z);
    tile[r][c4 + i + 3] = f2bf(v.w);
  }
  __syncthreads();
  u16 o[16];
#pragma unroll
  for (int i = 0; i < 16; ++i) o[i] = tile[c4 + i][r];
  u16* dst = WT + (size_t)(n0 + r) * 2560 + k0 + c4;
  *(bf16x8*)dst = *(bf16x8*)&o[0];
  *(bf16x8*)(dst + 8) = *(bf16x8*)&o[8];
}

// ---------------- GEMM: C = A(MxK,bf16) * BT(NxK,bf16)^T + bias(fp32) ----------------
// mode 0: out bf16 row-major MxN. mode 1: out bf16 V^T (B,32,80,2048). mode 2: out fp32 row-major.
__global__ __launch_bounds__(256) void gemm_bt(
    const u16* __restrict__ A, const u16* __restrict__ BT,
    const float* __restrict__ bias, void* __restrict__ outv,
    int M, int N, int K, int mode)
{
  __shared__ u16 As[128 * 64];
  __shared__ u16 Bs[128 * 64];
  const int tid = threadIdx.x;
  const int wid = tid >> 6, lane = tid & 63;
  const int l15 = lane & 15, g = lane >> 4;
  const int m0 = blockIdx.y * 128, n0 = blockIdx.x * 128;
  const int wr = wid >> 1, wc = wid & 1;

  f32x4 acc[4][4] = {};

  const u16* aT = A + (size_t)m0 * K;
  const u16* bT = BT + (size_t)n0 * K;

  for (int k0 = 0; k0 < K; k0 += 64) {
#pragma unroll
    for (int j = 0; j < 4; ++j) {
      int off = (wid * 4 + j) * 1024 + lane * 16;   // byte offset within 16KB tile
      int row = off >> 7;
      int ce  = (off & 127) >> 1;
      __builtin_amdgcn_global_load_lds(
          (const AS1 void*)(aT + (size_t)row * K + k0 + ce),
          (AS3 void*)((char*)As + (wid * 4 + j) * 1024), 16, 0, 0);
    }
#pragma unroll
    for (int j = 0; j < 4; ++j) {
      int off = (wid * 4 + j) * 1024 + lane * 16;
      int row = off >> 7;
      int ce  = (off & 127) >> 1;
      __builtin_amdgcn_global_load_lds(
          (const AS1 void*)(bT + (size_t)row * K + k0 + ce),
          (AS3 void*)((char*)Bs + (wid * 4 + j) * 1024), 16, 0, 0);
    }
    __syncthreads();
#pragma unroll
    for (int kk = 0; kk < 2; ++kk) {
      bf16x8 af[4], bfr[4];
#pragma unroll
      for (int i = 0; i < 4; ++i)
        af[i] = *(const bf16x8*)&As[(wr * 64 + i * 16 + l15) * 64 + kk * 32 + g * 8];
#pragma unroll
      for (int i = 0; i < 4; ++i)
        bfr[i] = *(const bf16x8*)&Bs[(wc * 64 + i * 16 + l15) * 64 + kk * 32 + g * 8];
#pragma unroll
      for (int i = 0; i < 4; ++i)
#pragma unroll
        for (int j = 0; j < 4; ++j)
          acc[i][j] = __builtin_amdgcn_mfma_f32_16x16x32_bf16(af[i], bfr[j], acc[i][j], 0, 0, 0);
    }
    __syncthreads();
  }

  float bv4[4];
#pragma unroll
  for (int j = 0; j < 4; ++j) bv4[j] = bias[n0 + wc * 64 + j * 16 + l15];

  if (mode == 0) {
    u16* out = (u16*)outv;
#pragma unroll
    for (int i = 0; i < 4; ++i) {
      int m = m0 + wr * 64 + i * 16 + 4 * g;
#pragma unroll
      for (int j = 0; j < 4; ++j) {
        int n = n0 + wc * 64 + j * 16 + l15;
#pragma unroll
        for (int r = 0; r < 4; ++r)
          out[(size_t)(m + r) * N + n] = f2bf(acc[i][j][r] + bv4[j]);
      }
    }
  } else if (mode == 1) {
    // V^T: (B,32,80,2048); n -> (h,d), m -> (b,s)
    u16* out = (u16*)outv;
#pragma unroll
    for (int j = 0; j < 4; ++j) {
      int n = n0 + wc * 64 + j * 16 + l15;
      int h = n / 80, d = n - h * 80;
#pragma unroll
      for (int i = 0; i < 4; ++i) {
        int m = m0 + wr * 64 + i * 16 + 4 * g;
        int b = m >> 11, s = m & 2047;
        bf16x4 pv;
#pragma unroll
        for (int r = 0; r < 4; ++r) pv[r] = (short)f2bf(acc[i][j][r] + bv4[j]);
        *(bf16x4*)&out[((size_t)((b * 32 + h) * 80 + d) << 11) + s] = pv;
      }
    }
  } else {
    float* out = (float*)outv;
#pragma unroll
    for (int i = 0; i < 4; ++i) {
      int m = m0 + wr * 64 + i * 16 + 4 * g;
#pragma unroll
      for (int j = 0; j < 4; ++j) {
        int n = n0 + wc * 64 + j * 16 + l15;
#pragma unroll
        for (int r = 0; r < 4; ++r)
          out[(size_t)(m + r) * N + n] = acc[i][j][r] + bv4[j];
      }
    }
  }
}

// ---------------- LayerNorm(2560) + partial RoPE(32 of 80) + head-split to (B,32,2048,96) ----------------
__global__ __launch_bounds__(320) void ln_rope(
    const u16* __restrict__ Qraw, const u16* __restrict__ Kraw,
    const float* __restrict__ qsc, const float* __restrict__ qbi,
    const float* __restrict__ ksc, const float* __restrict__ kbi,
    const float* __restrict__ sinT, const float* __restrict__ cosT,
    const int* __restrict__ pos_ids,
    u16* __restrict__ Qout, u16* __restrict__ Kout)
{
  __shared__ float ybuf[2560];
  __shared__ float red[10];
  const int row = blockIdx.x;         // b*2048 + s
  const int isK = blockIdx.y;
  const u16* raw   = isK ? Kraw : Qraw;
  const float* sc  = isK ? ksc : qsc;
  const float* bi  = isK ? kbi : qbi;
  u16* outp        = isK ? Kout : Qout;
  const int t = threadIdx.x;
  const int c0 = t * 8;
  bf16x8 v = *(const bf16x8*)(raw + (size_t)row * 2560 + c0);
  float x[8]; float s1 = 0.f, s2 = 0.f;
#pragma unroll
  for (int i = 0; i < 8; ++i) { x[i] = bf2f((u16)v[i]); s1 += x[i]; s2 += x[i] * x[i]; }
#pragma unroll
  for (int o = 32; o > 0; o >>= 1) { s1 += __shfl_xor(s1, o, 64); s2 += __shfl_xor(s2, o, 64); }
  const int wid = t >> 6, lane = t & 63;
  if (lane == 0) { red[wid] = s1; red[5 + wid] = s2; }
  __syncthreads();
  if (t == 0) {
    float a = 0.f, b2 = 0.f;
#pragma unroll
    for (int i = 0; i < 5; ++i) { a += red[i]; b2 += red[5 + i]; }
    red[0] = a; red[5] = b2;
  }
  __syncthreads();
  const float mean = red[0] * (1.f / 2560.f);
  const float var  = red[5] * (1.f / 2560.f) - mean * mean;
  const float rstd = rsqrtf(var + 1e-5f);
  float scv[8], biv[8];
  {
    float4 a0 = *(const float4*)(sc + c0), a1 = *(const float4*)(sc + c0 + 4);
    float4 b0 = *(const float4*)(bi + c0), b1 = *(const float4*)(bi + c0 + 4);
    scv[0]=a0.x; scv[1]=a0.y; scv[2]=a0.z; scv[3]=a0.w; scv[4]=a1.x; scv[5]=a1.y; scv[6]=a1.z; scv[7]=a1.w;
    biv[0]=b0.x; biv[1]=b0.y; biv[2]=b0.z; biv[3]=b0.w; biv[4]=b1.x; biv[5]=b1.y; biv[6]=b1.z; biv[7]=b1.w;
  }
  float y[8];
#pragma unroll
  for (int i = 0; i < 8; ++i) {
    y[i] = (x[i] - mean) * rstd * scv[i] + biv[i];
    ybuf[c0 + i] = y[i];
  }
  __syncthreads();
  const int pos = pos_ids[row];
  const int hh = c0 / 80, d0 = c0 - hh * 80;   // 8|80 -> all 8 elems same head
  bf16x8 ov;
#pragma unroll
  for (int i = 0; i < 8; ++i) {
    int d = d0 + i;
    float val;
    if (d < 16) {
      val = y[i] * cosT[pos * 32 + d] - ybuf[c0 + i + 16] * sinT[pos * 32 + d];
    } else if (d < 32) {
      val = y[i] * cosT[pos * 32 + d] + ybuf[c0 + i - 16] * sinT[pos * 32 + d];
    } else {
      val = y[i];
    }
    ov[i] = (short)f2bf(val);
  }
  const int bb = row >> 11, ss = row & 2047;
  u16* obase = outp + ((size_t)(bb * 32 + hh) * 2048 + ss) * 96;
  *(bf16x8*)(obase + d0) = ov;
  if (d0 == 72) {                 // zero-fill the d=80..95 pad
    bf16x8 z = {};
    *(bf16x8*)(obase + 80) = z;
    *(bf16x8*)(obase + 88) = z;
  }
}

// ---------------- causal flash attention ----------------
// Q,K: (B,32,2048,96) bf16 (d 80..95 zero); V^T: (B,32,80,2048) bf16; O: (4096, 2560) bf16 row-major.
__global__ __launch_bounds__(256) void attn_k(
    const u16* __restrict__ Qr, const u16* __restrict__ Kr,
    const u16* __restrict__ Vt, const int* __restrict__ amask,
    u16* __restrict__ O)
{
  __shared__ u16 Ks[64 * 96];    // 12KB, linear copy of K tile (rows of 96)
  __shared__ u16 Vs[80 * 64];    // 10KB, V^T tile [d][kv]
  __shared__ u16 Ps[4][16 * 64]; // per-wave P buffer
  const int tid = threadIdx.x;
  const int wid = tid >> 6, lane = tid & 63;
  const int l15 = lane & 15, g = lane >> 4;
  const int qb = blockIdx.x, h = blockIdx.y, b = blockIdx.z;
  const size_t bh = (size_t)b * 32 + h;
  const u16* qbase = Qr + bh * 2048 * 96;
  const u16* kbase = Kr + bh * 2048 * 96;
  const u16* vbase = Vt + bh * 80 * 2048;
  const int qw0 = qb * 64 + wid * 16;

  bf16x8 aq[3];
  {
    const u16* qp = qbase + (size_t)(qw0 + l15) * 96;
#pragma unroll
    for (int c = 0; c < 3; ++c) aq[c] = *(const bf16x8*)(qp + c * 32 + g * 8);
  }

  f32x4 acc_o[5] = {};
  float mrow[4] = {-3e38f, -3e38f, -3e38f, -3e38f};
  float lrow[4] = {0.f, 0.f, 0.f, 0.f};
  const float scl = 0.11180339887498949f;  // 1/sqrt(80)
  const int ntiles = qb + 1;

  for (int t = 0; t < ntiles; ++t) {
    {
      const char* kg = (const char*)(kbase + (size_t)t * 64 * 96);
      for (int j = wid; j < 12; j += 4) {
        __builtin_amdgcn_global_load_lds(
            (const AS1 void*)(kg + j * 1024 + lane * 16),
            (AS3 void*)((char*)Ks + j * 1024), 16, 0, 0);
      }
      const char* vg = (const char*)(vbase + t * 64);
      for (int j = wid; j < 10; j += 4) {
        int row = j * 8 + (lane >> 3);
        int cb  = (lane & 7) * 16;
        __builtin_amdgcn_global_load_lds(
            (const AS1 void*)(vg + (size_t)row * 4096 + cb),
            (AS3 void*)((char*)Vs + j * 1024), 16, 0, 0);
      }
    }
    __syncthreads();

    // S = Q K^T over padded d=96
    f32x4 sacc[4] = {};
#pragma unroll
    for (int kf = 0; kf < 4; ++kf) {
#pragma unroll
      for (int c = 0; c < 3; ++c) {
        bf16x8 bk_ = *(const bf16x8*)&Ks[(kf * 16 + l15) * 96 + c * 32 + g * 8];
        sacc[kf] = __builtin_amdgcn_mfma_f32_16x16x32_bf16(aq[c], bk_, sacc[kf], 0, 0, 0);
      }
    }

    // scale + causal + pad mask  (D layout: col = l15, row = 4g+r)
    const int kvb0 = t * 64;
#pragma unroll
    for (int kf = 0; kf < 4; ++kf) {
      int kv = kvb0 + kf * 16 + l15;
      bool pm = amask[b * 2048 + kv] > 0;
#pragma unroll
      for (int r = 0; r < 4; ++r) {
        float sv = sacc[kf][r] * scl;
        int q = qw0 + 4 * g + r;
        if (!pm || kv > q) sv = -3e38f;
        sacc[kf][r] = sv;
      }
    }

    // online softmax (per row r, reduce over the 16-lane group)
    float p[4][4];
    float cfv[4];
#pragma unroll
    for (int r = 0; r < 4; ++r) {
      float tm = fmaxf(fmaxf(sacc[0][r], sacc[1][r]), fmaxf(sacc[2][r], sacc[3][r]));
#pragma unroll
      for (int o = 1; o < 16; o <<= 1) tm = fmaxf(tm, __shfl_xor(tm, o, 64));
      float mn = fmaxf(mrow[r], tm);
      float c = __expf(mrow[r] - mn);
      cfv[r] = c;
      mrow[r] = mn;
      float ps = 0.f;
#pragma unroll
      for (int kf = 0; kf < 4; ++kf) {
        float e = __expf(sacc[kf][r] - mn);
        p[kf][r] = e;
        ps += e;
      }
      lrow[r] = lrow[r] * c + ps;
    }
#pragma unroll
    for (int nf = 0; nf < 5; ++nf)
#pragma unroll
      for (int r = 0; r < 4; ++r) acc_o[nf][r] *= cfv[r];

    // P -> wave-private LDS (re-fragment for PV)
    u16* pw = &Ps[wid][0];
#pragma unroll
    for (int kf = 0; kf < 4; ++kf)
#pragma unroll
      for (int r = 0; r < 4; ++r)
        pw[(4 * g + r) * 64 + kf * 16 + l15] = f2bf(p[kf][r]);

    // O += P V
#pragma unroll
    for (int c = 0; c < 2; ++c) {
      bf16x8 ap = *(const bf16x8*)&pw[l15 * 64 + c * 32 + g * 8];
#pragma unroll
      for (int nf = 0; nf < 5; ++nf) {
        bf16x8 bv_ = *(const bf16x8*)&Vs[(nf * 16 + l15) * 64 + c * 32 + g * 8];
        acc_o[nf] = __builtin_amdgcn_mfma_f32_16x16x32_bf16(ap, bv_, acc_o[nf], 0, 0, 0);
      }
    }
    __syncthreads();
  }

#pragma unroll
  for (int r = 0; r < 4; ++r) {
    float s = lrow[r];
#pragma unroll
    for (int o = 1; o < 16; o <<= 1) s += __shfl_xor(s, o, 64);
    lrow[r] = s;
  }
#pragma unroll
  for (int nf = 0; nf < 5; ++nf) {
    int d = nf * 16 + l15;
#pragma unroll
    for (int r = 0; r < 4; ++r) {
      int q = qw0 + 4 * g + r;
      O[(size_t)(b * 2048 + q) * 2560 + h * 80 + d] = f2bf(acc_o[nf][r] / lrow[r]);
    }
  }
}

extern "C" void kernel_launch(void* const* d_in, const int* in_sizes, int n_in,
                              void* d_out, int out_size, void* d_ws, size_t ws_size,
                              hipStream_t stream)
{
  const float* hs    = (const float*)d_in[0];
  const int*   amask = (const int*)d_in[1];
  const int*   pos   = (const int*)d_in[2];
  const float* sinT  = (const float*)d_in[3];
  const float* cosT  = (const float*)d_in[4];
  const float* Wq    = (const float*)d_in[5];
  const float* bq    = (const float*)d_in[6];
  const float* Wk    = (const float*)d_in[7];
  const float* bk    = (const float*)d_in[8];
  const float* Wv    = (const float*)d_in[9];
  const float* bv    = (const float*)d_in[10];
  const float* Wo    = (const float*)d_in[11];
  const float* bo    = (const float*)d_in[12];
  const float* qsc   = (const float*)d_in[13];
  const float* qbi   = (const float*)d_in[14];
  const float* ksc   = (const float*)d_in[15];
  const float* kbi   = (const float*)d_in[16];

  char* ws = (char*)d_ws;
  u16* WqT   = (u16*)(ws);                    // 13,107,200 B each
  u16* WkT   = (u16*)(ws + 13107200);
  u16* WvT   = (u16*)(ws + 26214400);
  u16* WoT   = (u16*)(ws + 39321600);
  u16* hs_bf = (u16*)(ws + 52428800);         // 20,971,520 B
  u16* Qraw  = (u16*)(ws + 73400320);         // 20,971,520 B
  u16* Kraw  = (u16*)(ws + 94371840);         // 20,971,520 B
  u16* Vt    = (u16*)(ws + 115343360);        // 20,971,520 B  (B,32,80,2048)
  u16* Qr    = (u16*)(ws);                    // 25,165,824 B, aliases WqT+WkT (dead by then)
  u16* Kr    = (u16*)(ws + 136314880);        // 25,165,824 B -> total 161,480,704 B
  u16* O     = Qraw;                          // Qraw dead after ln_rope

  cvt_hs<<<dim3(5120), 256, 0, stream>>>(hs, hs_bf);
  transp_k<<<dim3(40, 40, 4), 256, 0, stream>>>(Wq, Wk, Wv, Wo, WqT, WkT, WvT, WoT);
  gemm_bt<<<dim3(20, 32), 256, 0, stream>>>(hs_bf, WqT, bq, Qraw, 4096, 2560, 2560, 0);
  gemm_bt<<<dim3(20, 32), 256, 0, stream>>>(hs_bf, WkT, bk, Kraw, 4096, 2560, 2560, 0);
  gemm_bt<<<dim3(20, 32), 256, 0, stream>>>(hs_bf, WvT, bv, Vt,   4096, 2560, 2560, 1);
  ln_rope<<<dim3(4096, 2), 320, 0, stream>>>(Qraw, Kraw, qsc, qbi, ksc, kbi, sinT, cosT, pos, Qr, Kr);
  attn_k<<<dim3(32, 32, 2), 256, 0, stream>>>(Qr, Kr, Vt, amask, O);
  gemm_bt<<<dim3(20, 32), 256, 0, stream>>>(O, WoT, bo, d_out, 4096, 2560, 2560, 2);

  (void)in_sizes; (void)n_in; (void)out_size; (void)ws_size;
}

// Round 4
// 758.000 us; speedup vs baseline: 1.3289x; 1.3289x over previous
//
#include <hip/hip_runtime.h>

typedef unsigned short u16;
typedef __attribute__((ext_vector_type(8))) short bf16x8;
typedef __attribute__((ext_vector_type(4))) short bf16x4;
typedef __attribute__((ext_vector_type(4))) float f32x4;

#define AS1 __attribute__((address_space(1)))
#define AS3 __attribute__((address_space(3)))

__device__ __forceinline__ float bf2f(u16 u) {
  union { unsigned int i; float f; } v; v.i = ((unsigned int)u) << 16; return v.f;
}
__device__ __forceinline__ u16 f2bf(float f) {
  union { float f; unsigned int i; } v; v.f = f;
  return (u16)((v.i + 0x7fffu + ((v.i >> 16) & 1u)) >> 16);
}

// ---------------- hidden_states fp32 -> bf16 ----------------
__global__ __launch_bounds__(256) void cvt_hs(const float* __restrict__ in, u16* __restrict__ out) {
  size_t i = ((size_t)blockIdx.x * 256 + threadIdx.x) * 8;
  float4 a = *(const float4*)(in + i);
  float4 b = *(const float4*)(in + i + 4);
  bf16x8 o;
  o[0] = (short)f2bf(a.x); o[1] = (short)f2bf(a.y); o[2] = (short)f2bf(a.z); o[3] = (short)f2bf(a.w);
  o[4] = (short)f2bf(b.x); o[5] = (short)f2bf(b.y); o[6] = (short)f2bf(b.z); o[7] = (short)f2bf(b.w);
  *(bf16x8*)(out + i) = o;
}

// ---------------- weight transpose: W fp32 (2560 x 2560, K x N) -> WT bf16 (N x K) ----------------
__global__ __launch_bounds__(256) void transp_k(
    const float* __restrict__ Wq, const float* __restrict__ Wk,
    const float* __restrict__ Wv, const float* __restrict__ Wo,
    u16* __restrict__ WqT, u16* __restrict__ WkT,
    u16* __restrict__ WvT, u16* __restrict__ WoT)
{
  __shared__ u16 tile[64][65];
  const float* W; u16* WT;
  switch (blockIdx.z) {
    case 0: W = Wq; WT = WqT; break;
    case 1: W = Wk; WT = WkT; break;
    case 2: W = Wv; WT = WvT; break;
    default: W = Wo; WT = WoT; break;
  }
  const int n0 = blockIdx.x * 64, k0 = blockIdx.y * 64;
  const int t = threadIdx.x;
  const int r = t >> 2, c4 = (t & 3) * 16;
  const float* src = W + (size_t)(k0 + r) * 2560 + n0 + c4;
#pragma unroll
  for (int i = 0; i < 16; i += 4) {
    float4 v = *(const float4*)(src + i);
    tile[r][c4 + i + 0] = f2bf(v.x);
    tile[r][c4 + i + 1] = f2bf(v.y);
    tile[r][c4 + i + 2] = f2bf(v.z);
    tile[r][c4 + i + 3] = f2bf(v.w);
  }
  __syncthreads();
  u16 o[16];
#pragma unroll
  for (int i = 0; i < 16; ++i) o[i] = tile[c4 + i][r];
  u16* dst = WT + (size_t)(n0 + r) * 2560 + k0 + c4;
  *(bf16x8*)dst = *(bf16x8*)&o[0];
  *(bf16x8*)(dst + 8) = *(bf16x8*)&o[8];
}

// ---------------- fused QKV GEMM: A(4096x2560) x [WqT;WkT;WvT](7680x2560)^T ----------------
// n < 2560 -> Qraw row-major; n < 5120 -> Kraw row-major; else Vt (B,32,80,2048).
__global__ __launch_bounds__(256) void gemm_qkv(
    const u16* __restrict__ A, const u16* __restrict__ BT,
    const float* __restrict__ bq, const float* __restrict__ bk, const float* __restrict__ bv,
    u16* __restrict__ Qraw, u16* __restrict__ Kraw, u16* __restrict__ Vt)
{
  __shared__ u16 As[128 * 64];
  __shared__ u16 Bs[128 * 64];
  const int K = 2560;
  const int tid = threadIdx.x;
  const int wid = tid >> 6, lane = tid & 63;
  const int l15 = lane & 15, g = lane >> 4;
  const int m0 = blockIdx.y * 128, n0 = blockIdx.x * 128;
  const int which = blockIdx.x / 20;            // 0=Q 1=K 2=V (128 | 2560)
  const int nn0 = n0 - which * 2560;
  const int wr = wid >> 1, wc = wid & 1;

  f32x4 acc[4][4] = {};

  const u16* aT = A + (size_t)m0 * K;
  const u16* bT = BT + (size_t)n0 * K;

  for (int k0 = 0; k0 < K; k0 += 64) {
#pragma unroll
    for (int j = 0; j < 4; ++j) {
      int off = (wid * 4 + j) * 1024 + lane * 16;
      int row = off >> 7;
      int ce  = (off & 127) >> 1;
      __builtin_amdgcn_global_load_lds(
          (const AS1 void*)(aT + (size_t)row * K + k0 + ce),
          (AS3 void*)((char*)As + (wid * 4 + j) * 1024), 16, 0, 0);
    }
#pragma unroll
    for (int j = 0; j < 4; ++j) {
      int off = (wid * 4 + j) * 1024 + lane * 16;
      int row = off >> 7;
      int ce  = (off & 127) >> 1;
      __builtin_amdgcn_global_load_lds(
          (const AS1 void*)(bT + (size_t)row * K + k0 + ce),
          (AS3 void*)((char*)Bs + (wid * 4 + j) * 1024), 16, 0, 0);
    }
    __syncthreads();
#pragma unroll
    for (int kk = 0; kk < 2; ++kk) {
      bf16x8 af[4], bfr[4];
#pragma unroll
      for (int i = 0; i < 4; ++i)
        af[i] = *(const bf16x8*)&As[(wr * 64 + i * 16 + l15) * 64 + kk * 32 + g * 8];
#pragma unroll
      for (int i = 0; i < 4; ++i)
        bfr[i] = *(const bf16x8*)&Bs[(wc * 64 + i * 16 + l15) * 64 + kk * 32 + g * 8];
#pragma unroll
      for (int i = 0; i < 4; ++i)
#pragma unroll
        for (int j = 0; j < 4; ++j)
          acc[i][j] = __builtin_amdgcn_mfma_f32_16x16x32_bf16(af[i], bfr[j], acc[i][j], 0, 0, 0);
    }
    __syncthreads();
  }

  const float* bias = (which == 0) ? bq : ((which == 1) ? bk : bv);
  float bv4[4];
#pragma unroll
  for (int j = 0; j < 4; ++j) bv4[j] = bias[nn0 + wc * 64 + j * 16 + l15];

  if (which < 2) {
    u16* out = which ? Kraw : Qraw;
#pragma unroll
    for (int i = 0; i < 4; ++i) {
      int m = m0 + wr * 64 + i * 16 + 4 * g;
#pragma unroll
      for (int j = 0; j < 4; ++j) {
        int n = nn0 + wc * 64 + j * 16 + l15;
#pragma unroll
        for (int r = 0; r < 4; ++r)
          out[(size_t)(m + r) * 2560 + n] = f2bf(acc[i][j][r] + bv4[j]);
      }
    }
  } else {
#pragma unroll
    for (int j = 0; j < 4; ++j) {
      int n = nn0 + wc * 64 + j * 16 + l15;
      int h = n / 80, d = n - h * 80;
#pragma unroll
      for (int i = 0; i < 4; ++i) {
        int m = m0 + wr * 64 + i * 16 + 4 * g;
        int b = m >> 11, s = m & 2047;
        bf16x4 pv;
#pragma unroll
        for (int r = 0; r < 4; ++r) pv[r] = (short)f2bf(acc[i][j][r] + bv4[j]);
        *(bf16x4*)&Vt[((size_t)((b * 32 + h) * 80 + d) << 11) + s] = pv;
      }
    }
  }
}

// ---------------- o-proj GEMM: C = A(MxK,bf16) * BT(NxK,bf16)^T + bias(fp32), fp32 out ----------------
__global__ __launch_bounds__(256) void gemm_bt(
    const u16* __restrict__ A, const u16* __restrict__ BT,
    const float* __restrict__ bias, float* __restrict__ out,
    int M, int N, int K)
{
  __shared__ u16 As[128 * 64];
  __shared__ u16 Bs[128 * 64];
  const int tid = threadIdx.x;
  const int wid = tid >> 6, lane = tid & 63;
  const int l15 = lane & 15, g = lane >> 4;
  const int m0 = blockIdx.y * 128, n0 = blockIdx.x * 128;
  const int wr = wid >> 1, wc = wid & 1;

  f32x4 acc[4][4] = {};

  const u16* aT = A + (size_t)m0 * K;
  const u16* bT = BT + (size_t)n0 * K;

  for (int k0 = 0; k0 < K; k0 += 64) {
#pragma unroll
    for (int j = 0; j < 4; ++j) {
      int off = (wid * 4 + j) * 1024 + lane * 16;
      int row = off >> 7;
      int ce  = (off & 127) >> 1;
      __builtin_amdgcn_global_load_lds(
          (const AS1 void*)(aT + (size_t)row * K + k0 + ce),
          (AS3 void*)((char*)As + (wid * 4 + j) * 1024), 16, 0, 0);
    }
#pragma unroll
    for (int j = 0; j < 4; ++j) {
      int off = (wid * 4 + j) * 1024 + lane * 16;
      int row = off >> 7;
      int ce  = (off & 127) >> 1;
      __builtin_amdgcn_global_load_lds(
          (const AS1 void*)(bT + (size_t)row * K + k0 + ce),
          (AS3 void*)((char*)Bs + (wid * 4 + j) * 1024), 16, 0, 0);
    }
    __syncthreads();
#pragma unroll
    for (int kk = 0; kk < 2; ++kk) {
      bf16x8 af[4], bfr[4];
#pragma unroll
      for (int i = 0; i < 4; ++i)
        af[i] = *(const bf16x8*)&As[(wr * 64 + i * 16 + l15) * 64 + kk * 32 + g * 8];
#pragma unroll
      for (int i = 0; i < 4; ++i)
        bfr[i] = *(const bf16x8*)&Bs[(wc * 64 + i * 16 + l15) * 64 + kk * 32 + g * 8];
#pragma unroll
      for (int i = 0; i < 4; ++i)
#pragma unroll
        for (int j = 0; j < 4; ++j)
          acc[i][j] = __builtin_amdgcn_mfma_f32_16x16x32_bf16(af[i], bfr[j], acc[i][j], 0, 0, 0);
    }
    __syncthreads();
  }

  float bv4[4];
#pragma unroll
  for (int j = 0; j < 4; ++j) bv4[j] = bias[n0 + wc * 64 + j * 16 + l15];

#pragma unroll
  for (int i = 0; i < 4; ++i) {
    int m = m0 + wr * 64 + i * 16 + 4 * g;
#pragma unroll
    for (int j = 0; j < 4; ++j) {
      int n = n0 + wc * 64 + j * 16 + l15;
#pragma unroll
      for (int r = 0; r < 4; ++r)
        out[(size_t)(m + r) * N + n] = acc[i][j][r] + bv4[j];
    }
  }
}

// ---------------- LayerNorm(2560) + partial RoPE(32 of 80) + head-split to (B,32,2048,96) ----------------
__global__ __launch_bounds__(320) void ln_rope(
    const u16* __restrict__ Qraw, const u16* __restrict__ Kraw,
    const float* __restrict__ qsc, const float* __restrict__ qbi,
    const float* __restrict__ ksc, const float* __restrict__ kbi,
    const float* __restrict__ sinT, const float* __restrict__ cosT,
    const int* __restrict__ pos_ids,
    u16* __restrict__ Qout, u16* __restrict__ Kout)
{
  __shared__ float ybuf[2560];
  __shared__ float red[10];
  const int row = blockIdx.x;         // b*2048 + s
  const int isK = blockIdx.y;
  const u16* raw   = isK ? Kraw : Qraw;
  const float* sc  = isK ? ksc : qsc;
  const float* bi  = isK ? kbi : qbi;
  u16* outp        = isK ? Kout : Qout;
  const int t = threadIdx.x;
  const int c0 = t * 8;
  bf16x8 v = *(const bf16x8*)(raw + (size_t)row * 2560 + c0);
  float x[8]; float s1 = 0.f, s2 = 0.f;
#pragma unroll
  for (int i = 0; i < 8; ++i) { x[i] = bf2f((u16)v[i]); s1 += x[i]; s2 += x[i] * x[i]; }
#pragma unroll
  for (int o = 32; o > 0; o >>= 1) { s1 += __shfl_xor(s1, o, 64); s2 += __shfl_xor(s2, o, 64); }
  const int wid = t >> 6, lane = t & 63;
  if (lane == 0) { red[wid] = s1; red[5 + wid] = s2; }
  __syncthreads();
  if (t == 0) {
    float a = 0.f, b2 = 0.f;
#pragma unroll
    for (int i = 0; i < 5; ++i) { a += red[i]; b2 += red[5 + i]; }
    red[0] = a; red[5] = b2;
  }
  __syncthreads();
  const float mean = red[0] * (1.f / 2560.f);
  const float var  = red[5] * (1.f / 2560.f) - mean * mean;
  const float rstd = rsqrtf(var + 1e-5f);
  float scv[8], biv[8];
  {
    float4 a0 = *(const float4*)(sc + c0), a1 = *(const float4*)(sc + c0 + 4);
    float4 b0 = *(const float4*)(bi + c0), b1 = *(const float4*)(bi + c0 + 4);
    scv[0]=a0.x; scv[1]=a0.y; scv[2]=a0.z; scv[3]=a0.w; scv[4]=a1.x; scv[5]=a1.y; scv[6]=a1.z; scv[7]=a1.w;
    biv[0]=b0.x; biv[1]=b0.y; biv[2]=b0.z; biv[3]=b0.w; biv[4]=b1.x; biv[5]=b1.y; biv[6]=b1.z; biv[7]=b1.w;
  }
  float y[8];
#pragma unroll
  for (int i = 0; i < 8; ++i) {
    y[i] = (x[i] - mean) * rstd * scv[i] + biv[i];
    ybuf[c0 + i] = y[i];
  }
  __syncthreads();
  const int pos = pos_ids[row];
  const int hh = c0 / 80, d0 = c0 - hh * 80;   // 8|80 -> all 8 elems same head
  bf16x8 ov;
#pragma unroll
  for (int i = 0; i < 8; ++i) {
    int d = d0 + i;
    float val;
    if (d < 16) {
      val = y[i] * cosT[pos * 32 + d] - ybuf[c0 + i + 16] * sinT[pos * 32 + d];
    } else if (d < 32) {
      val = y[i] * cosT[pos * 32 + d] + ybuf[c0 + i - 16] * sinT[pos * 32 + d];
    } else {
      val = y[i];
    }
    ov[i] = (short)f2bf(val);
  }
  const int bb = row >> 11, ss = row & 2047;
  u16* obase = outp + ((size_t)(bb * 32 + hh) * 2048 + ss) * 96;
  *(bf16x8*)(obase + d0) = ov;
  if (d0 == 72) {                 // zero-fill the d=80..95 pad
    bf16x8 z = {};
    *(bf16x8*)(obase + 80) = z;
    *(bf16x8*)(obase + 88) = z;
  }
}

// ---------------- causal flash attention, balanced pairs + chunk-XOR-swizzled LDS ----------------
// Q,K: (B,32,2048,96) bf16 (d 80..95 zero); V^T: (B,32,80,2048); O: (4096,2560) bf16 row-major.
// Block x = pair index i: processes q-tiles {i, 31-i} -> exactly 33 kv-tile iterations/block.
// LDS: 16B-chunk XOR swizzle sc = lc ^ (row&7); global source pre-swizzled, dests linear (rule #21).
__global__ __launch_bounds__(256, 4) void attn_k(
    const u16* __restrict__ Qr, const u16* __restrict__ Kr,
    const u16* __restrict__ Vt, const int* __restrict__ amask,
    u16* __restrict__ O)
{
  __shared__ u16 Ks[64 * 128];   // 16KB: rows padded 96->128 u16 (16 chunks), swizzled
  __shared__ u16 Vs[80 * 64];    // 10KB: [d][kv], 8 chunks/row, swizzled
  __shared__ u16 Ps[4][16 * 64]; // 8KB per-wave P, swizzled
  const int tid = threadIdx.x;
  const int wid = tid >> 6, lane = tid & 63;
  const int l15 = lane & 15, g = lane >> 4;
  const int h = blockIdx.y, b = blockIdx.z;
  const size_t bh = (size_t)b * 32 + h;
  const u16* qbase = Qr + bh * 2048 * 96;
  const u16* kbase = Kr + bh * 2048 * 96;
  const u16* vbase = Vt + bh * 80 * 2048;
  const float scl = 0.11180339887498949f;  // 1/sqrt(80)
  u16* pw = &Ps[wid][0];
  const int lsw = (l15 & 7);               // read-side XOR key

  for (int ph = 0; ph < 2; ++ph) {
    const int qb = ph ? (31 - (int)blockIdx.x) : (int)blockIdx.x;
    const int qw0 = qb * 64 + wid * 16;

    bf16x8 aq[3];
    {
      const u16* qp = qbase + (size_t)(qw0 + l15) * 96;
#pragma unroll
      for (int c = 0; c < 3; ++c) aq[c] = *(const bf16x8*)(qp + c * 32 + g * 8);
    }

    f32x4 acc_o[5] = {};
    float mrow[4] = {-3e38f, -3e38f, -3e38f, -3e38f};
    float lrow[4] = {0.f, 0.f, 0.f, 0.f};
    const int ntiles = qb + 1;

    for (int t = 0; t < ntiles; ++t) {
      {
        // K tile: 64 rows x 96 u16 -> LDS [64][128], chunk-swizzled source
        const u16* kg = kbase + (size_t)t * 64 * 96;
#pragma unroll
        for (int j = 0; j < 4; ++j) {
          int chunk = j * 256 + tid;
          int row = chunk >> 4, scn = chunk & 15;
          int lc = scn ^ (row & 7);
          const u16* src = kg + (size_t)row * 96 + (lc < 12 ? lc * 8 : 0);
          __builtin_amdgcn_global_load_lds(
              (const AS1 void*)src,
              (AS3 void*)((char*)Ks + (j * 256 + wid * 64) * 16), 16, 0, 0);
        }
        // V tile: 80 rows x 64 u16, 640 chunks
        const u16* vg = vbase + t * 64;
#pragma unroll
        for (int k2 = 0; k2 < 3; ++k2) {
          int cbase = k2 * 256 + wid * 64;
          if (cbase < 640) {
            int chunk = cbase + lane;
            int d = chunk >> 3, scn = chunk & 7;
            int lc = scn ^ (d & 7);
            const u16* src = vg + (size_t)d * 2048 + lc * 8;
            __builtin_amdgcn_global_load_lds(
                (const AS1 void*)src,
                (AS3 void*)((char*)Vs + cbase * 16), 16, 0, 0);
          }
        }
      }
      __syncthreads();

      // S = Q K^T over padded d=96
      f32x4 sacc[4] = {};
#pragma unroll
      for (int kf = 0; kf < 4; ++kf) {
#pragma unroll
        for (int c = 0; c < 3; ++c) {
          bf16x8 bk_ = *(const bf16x8*)&Ks[(kf * 16 + l15) * 128 + ((c * 4 + g) ^ lsw) * 8];
          sacc[kf] = __builtin_amdgcn_mfma_f32_16x16x32_bf16(aq[c], bk_, sacc[kf], 0, 0, 0);
        }
      }

      // scale + causal + pad mask  (D layout: col = l15, row = 4g+r)
      const int kvb0 = t * 64;
#pragma unroll
      for (int kf = 0; kf < 4; ++kf) {
        int kv = kvb0 + kf * 16 + l15;
        bool pm = amask[b * 2048 + kv] > 0;
#pragma unroll
        for (int r = 0; r < 4; ++r) {
          float sv = sacc[kf][r] * scl;
          int q = qw0 + 4 * g + r;
          if (!pm || kv > q) sv = -3e38f;
          sacc[kf][r] = sv;
        }
      }

      // online softmax (per row r, reduce over the 16-lane group)
      float p[4][4];
      float cfv[4];
#pragma unroll
      for (int r = 0; r < 4; ++r) {
        float tm = fmaxf(fmaxf(sacc[0][r], sacc[1][r]), fmaxf(sacc[2][r], sacc[3][r]));
#pragma unroll
        for (int o = 1; o < 16; o <<= 1) tm = fmaxf(tm, __shfl_xor(tm, o, 64));
        float mn = fmaxf(mrow[r], tm);
        float c = __expf(mrow[r] - mn);
        cfv[r] = c;
        mrow[r] = mn;
        float ps = 0.f;
#pragma unroll
        for (int kf = 0; kf < 4; ++kf) {
          float e = __expf(sacc[kf][r] - mn);
          p[kf][r] = e;
          ps += e;
        }
        lrow[r] = lrow[r] * c + ps;
      }
#pragma unroll
      for (int nf = 0; nf < 5; ++nf)
#pragma unroll
        for (int r = 0; r < 4; ++r) acc_o[nf][r] *= cfv[r];

      // P -> wave-private LDS (re-fragment for PV), swizzled
#pragma unroll
      for (int kf = 0; kf < 4; ++kf)
#pragma unroll
        for (int r = 0; r < 4; ++r) {
          int prow = 4 * g + r;
          int pcol = kf * 16 + l15;
          pw[prow * 64 + ((pcol >> 3) ^ (prow & 7)) * 8 + (pcol & 7)] = f2bf(p[kf][r]);
        }

      // O += P V
#pragma unroll
      for (int c = 0; c < 2; ++c) {
        bf16x8 ap = *(const bf16x8*)&pw[l15 * 64 + ((c * 4 + g) ^ lsw) * 8];
#pragma unroll
        for (int nf = 0; nf < 5; ++nf) {
          bf16x8 bv_ = *(const bf16x8*)&Vs[(nf * 16 + l15) * 64 + ((c * 4 + g) ^ lsw) * 8];
          acc_o[nf] = __builtin_amdgcn_mfma_f32_16x16x32_bf16(ap, bv_, acc_o[nf], 0, 0, 0);
        }
      }
      __syncthreads();
    }

#pragma unroll
    for (int r = 0; r < 4; ++r) {
      float s = lrow[r];
#pragma unroll
      for (int o = 1; o < 16; o <<= 1) s += __shfl_xor(s, o, 64);
      lrow[r] = s;
    }
#pragma unroll
    for (int nf = 0; nf < 5; ++nf) {
      int d = nf * 16 + l15;
#pragma unroll
      for (int r = 0; r < 4; ++r) {
        int q = qw0 + 4 * g + r;
        O[(size_t)(b * 2048 + q) * 2560 + h * 80 + d] = f2bf(acc_o[nf][r] / lrow[r]);
      }
    }
  }
}

extern "C" void kernel_launch(void* const* d_in, const int* in_sizes, int n_in,
                              void* d_out, int out_size, void* d_ws, size_t ws_size,
                              hipStream_t stream)
{
  const float* hs    = (const float*)d_in[0];
  const int*   amask = (const int*)d_in[1];
  const int*   pos   = (const int*)d_in[2];
  const float* sinT  = (const float*)d_in[3];
  const float* cosT  = (const float*)d_in[4];
  const float* Wq    = (const float*)d_in[5];
  const float* bq    = (const float*)d_in[6];
  const float* Wk    = (const float*)d_in[7];
  const float* bk    = (const float*)d_in[8];
  const float* Wv    = (const float*)d_in[9];
  const float* bv    = (const float*)d_in[10];
  const float* Wo    = (const float*)d_in[11];
  const float* bo    = (const float*)d_in[12];
  const float* qsc   = (const float*)d_in[13];
  const float* qbi   = (const float*)d_in[14];
  const float* ksc   = (const float*)d_in[15];
  const float* kbi   = (const float*)d_in[16];

  char* ws = (char*)d_ws;
  u16* WqT   = (u16*)(ws);                    // 13,107,200 B each; Wq/Wk/Wv CONTIGUOUS for fused GEMM
  u16* WoT   = (u16*)(ws + 39321600);
  u16* hs_bf = (u16*)(ws + 52428800);         // 20,971,520 B
  u16* Qraw  = (u16*)(ws + 73400320);         // 20,971,520 B
  u16* Kraw  = (u16*)(ws + 94371840);         // 20,971,520 B
  u16* Vt    = (u16*)(ws + 115343360);        // 20,971,520 B  (B,32,80,2048)
  u16* Qr    = (u16*)(ws);                    // 25,165,824 B, aliases WqT+WkT (dead after gemm_qkv)
  u16* Kr    = (u16*)(ws + 136314880);        // 25,165,824 B -> total 161,480,704 B
  u16* WkT   = WqT + 2560 * 2560;
  u16* WvT   = WkT + 2560 * 2560;
  u16* O     = Qraw;                          // Qraw dead after ln_rope

  cvt_hs<<<dim3(5120), 256, 0, stream>>>(hs, hs_bf);
  transp_k<<<dim3(40, 40, 4), 256, 0, stream>>>(Wq, Wk, Wv, Wo, WqT, WkT, WvT, WoT);
  gemm_qkv<<<dim3(60, 32), 256, 0, stream>>>(hs_bf, WqT, bq, bk, bv, Qraw, Kraw, Vt);
  ln_rope<<<dim3(4096, 2), 320, 0, stream>>>(Qraw, Kraw, qsc, qbi, ksc, kbi, sinT, cosT, pos, Qr, Kr);
  attn_k<<<dim3(16, 32, 2), 256, 0, stream>>>(Qr, Kr, Vt, amask, O);
  gemm_bt<<<dim3(20, 32), 256, 0, stream>>>(O, WoT, bo, (float*)d_out, 4096, 2560, 2560);

  (void)in_sizes; (void)n_in; (void)out_size; (void)ws_size;
}

// Round 5
// 659.619 us; speedup vs baseline: 1.5271x; 1.1491x over previous
//
#include <hip/hip_runtime.h>

typedef unsigned short u16;
typedef __attribute__((ext_vector_type(8))) short bf16x8;
typedef __attribute__((ext_vector_type(4))) short bf16x4;
typedef __attribute__((ext_vector_type(4))) float f32x4;

#define AS1 __attribute__((address_space(1)))
#define AS3 __attribute__((address_space(3)))

__device__ __forceinline__ float bf2f(u16 u) {
  union { unsigned int i; float f; } v; v.i = ((unsigned int)u) << 16; return v.f;
}
__device__ __forceinline__ u16 f2bf(float f) {
  union { float f; unsigned int i; } v; v.f = f;
  return (u16)((v.i + 0x7fffu + ((v.i >> 16) & 1u)) >> 16);
}

// ---------------- hidden_states fp32 -> bf16 ----------------
__global__ __launch_bounds__(256) void cvt_hs(const float* __restrict__ in, u16* __restrict__ out) {
  size_t i = ((size_t)blockIdx.x * 256 + threadIdx.x) * 8;
  float4 a = *(const float4*)(in + i);
  float4 b = *(const float4*)(in + i + 4);
  bf16x8 o;
  o[0] = (short)f2bf(a.x); o[1] = (short)f2bf(a.y); o[2] = (short)f2bf(a.z); o[3] = (short)f2bf(a.w);
  o[4] = (short)f2bf(b.x); o[5] = (short)f2bf(b.y); o[6] = (short)f2bf(b.z); o[7] = (short)f2bf(b.w);
  *(bf16x8*)(out + i) = o;
}

// ---------------- weight transpose: W fp32 (2560 x 2560, K x N) -> WT bf16 (N x K) ----------------
__global__ __launch_bounds__(256) void transp_k(
    const float* __restrict__ Wq, const float* __restrict__ Wk,
    const float* __restrict__ Wv, const float* __restrict__ Wo,
    u16* __restrict__ WqT, u16* __restrict__ WkT,
    u16* __restrict__ WvT, u16* __restrict__ WoT)
{
  __shared__ u16 tile[64][65];
  const float* W; u16* WT;
  switch (blockIdx.z) {
    case 0: W = Wq; WT = WqT; break;
    case 1: W = Wk; WT = WkT; break;
    case 2: W = Wv; WT = WvT; break;
    default: W = Wo; WT = WoT; break;
  }
  const int n0 = blockIdx.x * 64, k0 = blockIdx.y * 64;
  const int t = threadIdx.x;
  const int r = t >> 2, c4 = (t & 3) * 16;
  const float* src = W + (size_t)(k0 + r) * 2560 + n0 + c4;
#pragma unroll
  for (int i = 0; i < 16; i += 4) {
    float4 v = *(const float4*)(src + i);
    tile[r][c4 + i + 0] = f2bf(v.x);
    tile[r][c4 + i + 1] = f2bf(v.y);
    tile[r][c4 + i + 2] = f2bf(v.z);
    tile[r][c4 + i + 3] = f2bf(v.w);
  }
  __syncthreads();
  u16 o[16];
#pragma unroll
  for (int i = 0; i < 16; ++i) o[i] = tile[c4 + i][r];
  u16* dst = WT + (size_t)(n0 + r) * 2560 + k0 + c4;
  *(bf16x8*)dst = *(bf16x8*)&o[0];
  *(bf16x8*)(dst + 8) = *(bf16x8*)&o[8];
}

// ---------------- 256x256 counted-vmcnt GEMM (T2 swizzle + T3/T4 counted waits + T5) ----
// A: (4096 x 2560) bf16 row-major. BT: (N x 2560) bf16 row-major (N-major).
// MODE 0: N=7680 QKV fused -> Q/K row-major bf16, V -> V^T (B,32,80,2048).
// MODE 1: N=2560 o-proj -> fp32 row-major out (o0), bias b0p.
template <int MODE>
__global__ __launch_bounds__(512, 2) void gemm256(
    const u16* __restrict__ A, const u16* __restrict__ BT,
    const float* __restrict__ b0p, const float* __restrict__ b1p, const float* __restrict__ b2p,
    void* __restrict__ o0, void* __restrict__ o1, void* __restrict__ o2)
{
  __shared__ u16 As[2][256 * 64];   // 64 KB
  __shared__ u16 Bs[2][256 * 64];   // 64 KB
  const int K = 2560, NT = 40;      // K / 64
  const int tid = threadIdx.x;
  const int wid = tid >> 6, lane = tid & 63;
  const int l15 = lane & 15, g = lane >> 4;
  const int wm = wid >> 2, wn = wid & 3;          // 2M x 4N waves
  const int m0 = blockIdx.y * 256, n0 = blockIdx.x * 256;

  // staging geometry: inst i covers rows i*64..i*64+63 of the 256-row tile;
  // thread -> row = i*64 + tid/8, LDS chunk cj = tid&7, source chunk lc = cj ^ (row&7).
  const int srow = tid >> 3;
  const int slc  = (tid & 7) ^ (srow & 7);
  const u16* aT = A + (size_t)(m0 + srow) * K + slc * 8;
  const u16* bT = BT + (size_t)(n0 + srow) * K + slc * 8;

#define STAGE(pb, kt)                                                              \
  {                                                                                \
    const u16* a_ = aT + (size_t)(kt) * 64;                                        \
    const u16* b_ = bT + (size_t)(kt) * 64;                                        \
    char* la = (char*)&As[pb][0] + wid * 1024 + lane * 16;                         \
    char* lb = (char*)&Bs[pb][0] + wid * 1024 + lane * 16;                         \
    _Pragma("unroll")                                                              \
    for (int i_ = 0; i_ < 4; ++i_) {                                               \
      __builtin_amdgcn_global_load_lds((const AS1 void*)(a_ + (size_t)i_ * 64 * K),\
                                       (AS3 void*)(la + i_ * 8192), 16, 0, 0);     \
      __builtin_amdgcn_global_load_lds((const AS1 void*)(b_ + (size_t)i_ * 64 * K),\
                                       (AS3 void*)(lb + i_ * 8192), 16, 0, 0);     \
    }                                                                              \
  }

  f32x4 acc[8][4] = {};

  STAGE(0, 0);
  STAGE(1, 1);
  asm volatile("s_waitcnt vmcnt(8)" ::: "memory");  // tile 0 landed; tile 1 in flight
  __builtin_amdgcn_s_barrier();
  __builtin_amdgcn_sched_barrier(0);

  for (int t = 0; t < NT; ++t) {
    const int p = t & 1;
    const u16* as = &As[p][0];
    const u16* bs = &Bs[p][0];
#pragma unroll
    for (int kk = 0; kk < 2; ++kk) {
      bf16x8 af[8], bfv[4];
      const int cj = ((kk * 4 + g) ^ (l15 & 7)) * 8;
#pragma unroll
      for (int m = 0; m < 8; ++m)
        af[m] = *(const bf16x8*)&as[(wm * 128 + m * 16 + l15) * 64 + cj];
#pragma unroll
      for (int n = 0; n < 4; ++n)
        bfv[n] = *(const bf16x8*)&bs[(wn * 64 + n * 16 + l15) * 64 + cj];
      __builtin_amdgcn_s_setprio(1);
#pragma unroll
      for (int m = 0; m < 8; ++m)
#pragma unroll
        for (int n = 0; n < 4; ++n)
          acc[m][n] = __builtin_amdgcn_mfma_f32_16x16x32_bf16(af[m], bfv[n], acc[m][n], 0, 0, 0);
      __builtin_amdgcn_s_setprio(0);
    }
    __builtin_amdgcn_s_barrier();               // all waves done reading buf[p]
    __builtin_amdgcn_sched_barrier(0);
    if (t + 2 < NT) {
      STAGE(p, t + 2);                          // overwrite buf[p] with tile t+2
      asm volatile("s_waitcnt vmcnt(8)" ::: "memory");  // tile t+1 confirmed; t+2 in flight
      __builtin_amdgcn_s_barrier();
      __builtin_amdgcn_sched_barrier(0);
    } else if (t + 1 < NT) {
      asm volatile("s_waitcnt vmcnt(0)" ::: "memory");  // drain final tile
      __builtin_amdgcn_s_barrier();
      __builtin_amdgcn_sched_barrier(0);
    }
  }
#undef STAGE

  if (MODE == 0) {
    const int which = n0 / 2560;                 // 0=Q 1=K 2=V (256 | 2560)
    const int nn0 = n0 - which * 2560;
    const float* bias = (which == 0) ? b0p : ((which == 1) ? b1p : b2p);
    float bvv[4];
#pragma unroll
    for (int n = 0; n < 4; ++n) bvv[n] = bias[nn0 + wn * 64 + n * 16 + l15];
    if (which < 2) {
      u16* out = which ? (u16*)o1 : (u16*)o0;
#pragma unroll
      for (int m = 0; m < 8; ++m) {
        int mm = m0 + wm * 128 + m * 16 + 4 * g;
#pragma unroll
        for (int n = 0; n < 4; ++n) {
          int nn = nn0 + wn * 64 + n * 16 + l15;
#pragma unroll
          for (int r = 0; r < 4; ++r)
            out[(size_t)(mm + r) * 2560 + nn] = f2bf(acc[m][n][r] + bvv[n]);
        }
      }
    } else {
      u16* Vt = (u16*)o2;
#pragma unroll
      for (int n = 0; n < 4; ++n) {
        int nn = nn0 + wn * 64 + n * 16 + l15;
        int h = nn / 80, d = nn - h * 80;
#pragma unroll
        for (int m = 0; m < 8; ++m) {
          int mm = m0 + wm * 128 + m * 16 + 4 * g;
          int b = mm >> 11, s = mm & 2047;
          bf16x4 pv;
#pragma unroll
          for (int r = 0; r < 4; ++r) pv[r] = (short)f2bf(acc[m][n][r] + bvv[n]);
          *(bf16x4*)&Vt[((size_t)((b * 32 + h) * 80 + d) << 11) + s] = pv;
        }
      }
    }
  } else {
    float* out = (float*)o0;
    float bvv[4];
#pragma unroll
    for (int n = 0; n < 4; ++n) bvv[n] = b0p[n0 + wn * 64 + n * 16 + l15];
#pragma unroll
    for (int m = 0; m < 8; ++m) {
      int mm = m0 + wm * 128 + m * 16 + 4 * g;
#pragma unroll
      for (int n = 0; n < 4; ++n) {
        int nn = n0 + wn * 64 + n * 16 + l15;
#pragma unroll
        for (int r = 0; r < 4; ++r)
          out[(size_t)(mm + r) * 2560 + nn] = acc[m][n][r] + bvv[n];
      }
    }
  }
}

// ---------------- LayerNorm(2560) + partial RoPE(32 of 80) + head-split to (B,32,2048,96) ----------------
__global__ __launch_bounds__(320) void ln_rope(
    const u16* __restrict__ Qraw, const u16* __restrict__ Kraw,
    const float* __restrict__ qsc, const float* __restrict__ qbi,
    const float* __restrict__ ksc, const float* __restrict__ kbi,
    const float* __restrict__ sinT, const float* __restrict__ cosT,
    const int* __restrict__ pos_ids,
    u16* __restrict__ Qout, u16* __restrict__ Kout)
{
  __shared__ float ybuf[2560];
  __shared__ float red[10];
  const int row = blockIdx.x;         // b*2048 + s
  const int isK = blockIdx.y;
  const u16* raw   = isK ? Kraw : Qraw;
  const float* sc  = isK ? ksc : qsc;
  const float* bi  = isK ? kbi : qbi;
  u16* outp        = isK ? Kout : Qout;
  const int t = threadIdx.x;
  const int c0 = t * 8;
  bf16x8 v = *(const bf16x8*)(raw + (size_t)row * 2560 + c0);
  float x[8]; float s1 = 0.f, s2 = 0.f;
#pragma unroll
  for (int i = 0; i < 8; ++i) { x[i] = bf2f((u16)v[i]); s1 += x[i]; s2 += x[i] * x[i]; }
#pragma unroll
  for (int o = 32; o > 0; o >>= 1) { s1 += __shfl_xor(s1, o, 64); s2 += __shfl_xor(s2, o, 64); }
  const int wid = t >> 6, lane = t & 63;
  if (lane == 0) { red[wid] = s1; red[5 + wid] = s2; }
  __syncthreads();
  if (t == 0) {
    float a = 0.f, b2 = 0.f;
#pragma unroll
    for (int i = 0; i < 5; ++i) { a += red[i]; b2 += red[5 + i]; }
    red[0] = a; red[5] = b2;
  }
  __syncthreads();
  const float mean = red[0] * (1.f / 2560.f);
  const float var  = red[5] * (1.f / 2560.f) - mean * mean;
  const float rstd = rsqrtf(var + 1e-5f);
  float scv[8], biv[8];
  {
    float4 a0 = *(const float4*)(sc + c0), a1 = *(const float4*)(sc + c0 + 4);
    float4 b0 = *(const float4*)(bi + c0), b1 = *(const float4*)(bi + c0 + 4);
    scv[0]=a0.x; scv[1]=a0.y; scv[2]=a0.z; scv[3]=a0.w; scv[4]=a1.x; scv[5]=a1.y; scv[6]=a1.z; scv[7]=a1.w;
    biv[0]=b0.x; biv[1]=b0.y; biv[2]=b0.z; biv[3]=b0.w; biv[4]=b1.x; biv[5]=b1.y; biv[6]=b1.z; biv[7]=b1.w;
  }
  float y[8];
#pragma unroll
  for (int i = 0; i < 8; ++i) {
    y[i] = (x[i] - mean) * rstd * scv[i] + biv[i];
    ybuf[c0 + i] = y[i];
  }
  __syncthreads();
  const int pos = pos_ids[row];
  const int hh = c0 / 80, d0 = c0 - hh * 80;   // 8|80 -> all 8 elems same head
  bf16x8 ov;
#pragma unroll
  for (int i = 0; i < 8; ++i) {
    int d = d0 + i;
    float val;
    if (d < 16) {
      val = y[i] * cosT[pos * 32 + d] - ybuf[c0 + i + 16] * sinT[pos * 32 + d];
    } else if (d < 32) {
      val = y[i] * cosT[pos * 32 + d] + ybuf[c0 + i - 16] * sinT[pos * 32 + d];
    } else {
      val = y[i];
    }
    ov[i] = (short)f2bf(val);
  }
  const int bb = row >> 11, ss = row & 2047;
  u16* obase = outp + ((size_t)(bb * 32 + hh) * 2048 + ss) * 96;
  *(bf16x8*)(obase + d0) = ov;
  if (d0 == 72) {                 // zero-fill the d=80..95 pad
    bf16x8 z = {};
    *(bf16x8*)(obase + 80) = z;
    *(bf16x8*)(obase + 88) = z;
  }
}

// ---------------- causal flash attention, balanced pairs + chunk-XOR-swizzled LDS ----------------
__global__ __launch_bounds__(256, 4) void attn_k(
    const u16* __restrict__ Qr, const u16* __restrict__ Kr,
    const u16* __restrict__ Vt, const int* __restrict__ amask,
    u16* __restrict__ O)
{
  __shared__ u16 Ks[64 * 128];   // 16KB: rows padded 96->128 u16 (16 chunks), swizzled
  __shared__ u16 Vs[80 * 64];    // 10KB: [d][kv], 8 chunks/row, swizzled
  __shared__ u16 Ps[4][16 * 64]; // 8KB per-wave P, swizzled
  const int tid = threadIdx.x;
  const int wid = tid >> 6, lane = tid & 63;
  const int l15 = lane & 15, g = lane >> 4;
  const int h = blockIdx.y, b = blockIdx.z;
  const size_t bh = (size_t)b * 32 + h;
  const u16* qbase = Qr + bh * 2048 * 96;
  const u16* kbase = Kr + bh * 2048 * 96;
  const u16* vbase = Vt + bh * 80 * 2048;
  const float scl = 0.11180339887498949f;  // 1/sqrt(80)
  u16* pw = &Ps[wid][0];
  const int lsw = (l15 & 7);               // read-side XOR key

  for (int ph = 0; ph < 2; ++ph) {
    const int qb = ph ? (31 - (int)blockIdx.x) : (int)blockIdx.x;
    const int qw0 = qb * 64 + wid * 16;

    bf16x8 aq[3];
    {
      const u16* qp = qbase + (size_t)(qw0 + l15) * 96;
#pragma unroll
      for (int c = 0; c < 3; ++c) aq[c] = *(const bf16x8*)(qp + c * 32 + g * 8);
    }

    f32x4 acc_o[5] = {};
    float mrow[4] = {-3e38f, -3e38f, -3e38f, -3e38f};
    float lrow[4] = {0.f, 0.f, 0.f, 0.f};
    const int ntiles = qb + 1;

    for (int t = 0; t < ntiles; ++t) {
      {
        const u16* kg = kbase + (size_t)t * 64 * 96;
#pragma unroll
        for (int j = 0; j < 4; ++j) {
          int chunk = j * 256 + tid;
          int row = chunk >> 4, scn = chunk & 15;
          int lc = scn ^ (row & 7);
          const u16* src = kg + (size_t)row * 96 + (lc < 12 ? lc * 8 : 0);
          __builtin_amdgcn_global_load_lds(
              (const AS1 void*)src,
              (AS3 void*)((char*)Ks + (j * 256 + wid * 64) * 16), 16, 0, 0);
        }
        const u16* vg = vbase + t * 64;
#pragma unroll
        for (int k2 = 0; k2 < 3; ++k2) {
          int cbase = k2 * 256 + wid * 64;
          if (cbase < 640) {
            int chunk = cbase + lane;
            int d = chunk >> 3, scn = chunk & 7;
            int lc = scn ^ (d & 7);
            const u16* src = vg + (size_t)d * 2048 + lc * 8;
            __builtin_amdgcn_global_load_lds(
                (const AS1 void*)src,
                (AS3 void*)((char*)Vs + cbase * 16), 16, 0, 0);
          }
        }
      }
      __syncthreads();

      // S = Q K^T over padded d=96
      f32x4 sacc[4] = {};
#pragma unroll
      for (int kf = 0; kf < 4; ++kf) {
#pragma unroll
        for (int c = 0; c < 3; ++c) {
          bf16x8 bk_ = *(const bf16x8*)&Ks[(kf * 16 + l15) * 128 + ((c * 4 + g) ^ lsw) * 8];
          sacc[kf] = __builtin_amdgcn_mfma_f32_16x16x32_bf16(aq[c], bk_, sacc[kf], 0, 0, 0);
        }
      }

      const int kvb0 = t * 64;
#pragma unroll
      for (int kf = 0; kf < 4; ++kf) {
        int kv = kvb0 + kf * 16 + l15;
        bool pm = amask[b * 2048 + kv] > 0;
#pragma unroll
        for (int r = 0; r < 4; ++r) {
          float sv = sacc[kf][r] * scl;
          int q = qw0 + 4 * g + r;
          if (!pm || kv > q) sv = -3e38f;
          sacc[kf][r] = sv;
        }
      }

      float p[4][4];
      float cfv[4];
#pragma unroll
      for (int r = 0; r < 4; ++r) {
        float tm = fmaxf(fmaxf(sacc[0][r], sacc[1][r]), fmaxf(sacc[2][r], sacc[3][r]));
#pragma unroll
        for (int o = 1; o < 16; o <<= 1) tm = fmaxf(tm, __shfl_xor(tm, o, 64));
        float mn = fmaxf(mrow[r], tm);
        float c = __expf(mrow[r] - mn);
        cfv[r] = c;
        mrow[r] = mn;
        float ps = 0.f;
#pragma unroll
        for (int kf = 0; kf < 4; ++kf) {
          float e = __expf(sacc[kf][r] - mn);
          p[kf][r] = e;
          ps += e;
        }
        lrow[r] = lrow[r] * c + ps;
      }
#pragma unroll
      for (int nf = 0; nf < 5; ++nf)
#pragma unroll
        for (int r = 0; r < 4; ++r) acc_o[nf][r] *= cfv[r];

#pragma unroll
      for (int kf = 0; kf < 4; ++kf)
#pragma unroll
        for (int r = 0; r < 4; ++r) {
          int prow = 4 * g + r;
          int pcol = kf * 16 + l15;
          pw[prow * 64 + ((pcol >> 3) ^ (prow & 7)) * 8 + (pcol & 7)] = f2bf(p[kf][r]);
        }

#pragma unroll
      for (int c = 0; c < 2; ++c) {
        bf16x8 ap = *(const bf16x8*)&pw[l15 * 64 + ((c * 4 + g) ^ lsw) * 8];
#pragma unroll
        for (int nf = 0; nf < 5; ++nf) {
          bf16x8 bv_ = *(const bf16x8*)&Vs[(nf * 16 + l15) * 64 + ((c * 4 + g) ^ lsw) * 8];
          acc_o[nf] = __builtin_amdgcn_mfma_f32_16x16x32_bf16(ap, bv_, acc_o[nf], 0, 0, 0);
        }
      }
      __syncthreads();
    }

#pragma unroll
    for (int r = 0; r < 4; ++r) {
      float s = lrow[r];
#pragma unroll
      for (int o = 1; o < 16; o <<= 1) s += __shfl_xor(s, o, 64);
      lrow[r] = s;
    }
#pragma unroll
    for (int nf = 0; nf < 5; ++nf) {
      int d = nf * 16 + l15;
#pragma unroll
      for (int r = 0; r < 4; ++r) {
        int q = qw0 + 4 * g + r;
        O[(size_t)(b * 2048 + q) * 2560 + h * 80 + d] = f2bf(acc_o[nf][r] / lrow[r]);
      }
    }
  }
}

extern "C" void kernel_launch(void* const* d_in, const int* in_sizes, int n_in,
                              void* d_out, int out_size, void* d_ws, size_t ws_size,
                              hipStream_t stream)
{
  const float* hs    = (const float*)d_in[0];
  const int*   amask = (const int*)d_in[1];
  const int*   pos   = (const int*)d_in[2];
  const float* sinT  = (const float*)d_in[3];
  const float* cosT  = (const float*)d_in[4];
  const float* Wq    = (const float*)d_in[5];
  const float* bq    = (const float*)d_in[6];
  const float* Wk    = (const float*)d_in[7];
  const float* bk    = (const float*)d_in[8];
  const float* Wv    = (const float*)d_in[9];
  const float* bv    = (const float*)d_in[10];
  const float* Wo    = (const float*)d_in[11];
  const float* bo    = (const float*)d_in[12];
  const float* qsc   = (const float*)d_in[13];
  const float* qbi   = (const float*)d_in[14];
  const float* ksc   = (const float*)d_in[15];
  const float* kbi   = (const float*)d_in[16];

  char* ws = (char*)d_ws;
  u16* WqT   = (u16*)(ws);                    // 13,107,200 B each; Wq/Wk/Wv CONTIGUOUS for fused GEMM
  u16* WoT   = (u16*)(ws + 39321600);
  u16* hs_bf = (u16*)(ws + 52428800);         // 20,971,520 B
  u16* Qraw  = (u16*)(ws + 73400320);         // 20,971,520 B
  u16* Kraw  = (u16*)(ws + 94371840);         // 20,971,520 B
  u16* Vt    = (u16*)(ws + 115343360);        // 20,971,520 B  (B,32,80,2048)
  u16* Qr    = (u16*)(ws);                    // 25,165,824 B, aliases WqT+WkT (dead after gemm_qkv)
  u16* Kr    = (u16*)(ws + 136314880);        // 25,165,824 B -> total 161,480,704 B
  u16* WkT   = WqT + 2560 * 2560;
  u16* WvT   = WkT + 2560 * 2560;
  u16* O     = Qraw;                          // Qraw dead after ln_rope

  cvt_hs<<<dim3(5120), 256, 0, stream>>>(hs, hs_bf);
  transp_k<<<dim3(40, 40, 4), 256, 0, stream>>>(Wq, Wk, Wv, Wo, WqT, WkT, WvT, WoT);
  gemm256<0><<<dim3(30, 16), 512, 0, stream>>>(hs_bf, WqT, bq, bk, bv, Qraw, Kraw, Vt);
  ln_rope<<<dim3(4096, 2), 320, 0, stream>>>(Qraw, Kraw, qsc, qbi, ksc, kbi, sinT, cosT, pos, Qr, Kr);
  attn_k<<<dim3(16, 32, 2), 256, 0, stream>>>(Qr, Kr, Vt, amask, O);
  gemm256<1><<<dim3(10, 16), 512, 0, stream>>>(O, WoT, bo, nullptr, nullptr, d_out, nullptr, nullptr);

  (void)in_sizes; (void)n_in; (void)out_size; (void)ws_size;
}